// Round 2
// baseline (882.940 us; speedup 1.0000x reference)
//
#include <hip/hip_runtime.h>
#include <hip/hip_cooperative_groups.h>
#include <stdint.h>

// MSAColumnGlobalAttention: B=1, S=2048, R=384, D=64, H=8, C=8, HC=64
// v4: single cooperative fused kernel (phase1 LN+kv+qpart, grid.sync,
// phase2 attention (384 blocks), grid.sync, phase3 gate+out+residual).
// Grid 768 blocks = 256 CU x 3 (LDS 44.3KB -> 3/CU, launch_bounds(256,3)
// -> <=168 VGPR -> 3 waves/SIMD). Phase2 head-split (2x4 heads) keeps
// register arrays at l[32]+ao[32]. Fallback: round-1 three-kernel path.

#define DEV __device__ __forceinline__

namespace cg = cooperative_groups;

typedef __attribute__((ext_vector_type(8))) short short8;   // 8 bf16 (4 VGPRs) MFMA A/B frag
typedef __attribute__((ext_vector_type(4))) float floatx4;  // MFMA C/D frag

static constexpr int S_DIM = 2048;
static constexpr int R_DIM = 384;
static constexpr int NCH   = 32;    // s-chunks of 64

// ws layout (bytes)
static constexpr size_t KV_OFF    = 0;         // bf16 [384][2048][16] (k0..7, v0..7) = 25165824
static constexpr size_t QPART_OFF = 25165824;  // f32  [384][32][72]  (64 q sums + cnt) = 3538944
static constexpr size_t O_OFF     = 28704768;  // f32  [384][64]

DEV float bf2f(uint32_t u) { union { uint32_t i; float f; } c; c.i = u << 16; return c.f; }
DEV uint16_t f2bf(float f) {
  union { float f; uint32_t i; } c; c.f = f;
  return (uint16_t)((c.i + 0x7FFFu + ((c.i >> 16) & 1u)) >> 16); // RNE
}
DEV void unpack8(uint4 w, float* x) {
  x[0] = bf2f(w.x & 0xffff); x[1] = bf2f(w.x >> 16);
  x[2] = bf2f(w.y & 0xffff); x[3] = bf2f(w.y >> 16);
  x[4] = bf2f(w.z & 0xffff); x[5] = bf2f(w.z >> 16);
  x[6] = bf2f(w.w & 0xffff); x[7] = bf2f(w.w >> 16);
}

// ============================ fused cooperative kernel ============================
__global__ __launch_bounds__(256, 3) void fused_all(
    const float* __restrict__ M, const float* __restrict__ mask,
    const float* __restrict__ lng, const float* __restrict__ lnb,
    const float* __restrict__ Wq, const float* __restrict__ Wk,
    const float* __restrict__ Wv, const float* __restrict__ Wg,
    const float* __restrict__ bg, const float* __restrict__ Wo,
    const float* __restrict__ bo, float* __restrict__ out,
    uint16_t* __restrict__ kv, float* __restrict__ qpart, float* __restrict__ oG)
{
  __shared__ __align__(16) char smem[44288];
  cg::grid_group grid = cg::this_grid();

  const int tid = threadIdx.x;
  const int w = tid >> 6, lane = tid & 63;
  const int rl = lane >> 4, c4 = lane & 15;
  const int sc = blockIdx.x;
  const int s0 = sc * 64;
  const int r0w = blockIdx.y * 16 + w * 4;

  // ---------------- Phase 1: LN + kv (MFMA) + masked-q partials ----------------
  {
    uint16_t* WkvT = (uint16_t*)smem;                        // [16][72]
    uint16_t* mA   = (uint16_t*)(smem + 2304) + w * 1152;    // per-wave [16][72]
    uint16_t* kS   = (uint16_t*)(smem + 11520) + w * 4096;   // per-wave [4][64][16]

#pragma unroll
    for (int i = 0; i < 4; ++i) {
      const int e = i * 256 + tid;         // 1024 elems
      const int n = e >> 6, d = e & 63;
      const float val = (n < 8) ? Wk[d * 8 + n] : Wv[d * 8 + (n - 8)];
      WkvT[n * 72 + d] = f2bf(val);
    }
    const float4 lngv = ((const float4*)lng)[c4];
    const float4 lnbv = ((const float4*)lnb)[c4];
    __syncthreads();

    // B fragments: B[n = c4][k = rl*8 + j (+32)]
    const short8 b0 = *(const short8*)&WkvT[c4 * 72 + rl * 8];
    const short8 b1 = *(const short8*)&WkvT[c4 * 72 + 32 + rl * 8];

    float qacc[4] = {0.f, 0.f, 0.f, 0.f};
    float cacc = 0.f;

#pragma unroll 2
    for (int grp = 0; grp < 16; ++grp) {
      const int sg = s0 + grp * 4;
      float4 xg[4];
      float mv[4];
#pragma unroll
      for (int si = 0; si < 4; ++si) {
        const size_t grow = (size_t)(sg + si) * R_DIM + r0w + rl;
        xg[si] = ((const float4*)(M + grow * 64))[c4];   // 1KB contiguous / wave
        mv[si] = mask[grow];
      }
#pragma unroll
      for (int si = 0; si < 4; ++si) {
        const float4 x = xg[si];
        float sum = x.x + x.y + x.z + x.w;
        float ss = x.x * x.x + x.y * x.y + x.z * x.z + x.w * x.w;
#pragma unroll
        for (int off = 1; off < 16; off <<= 1) {
          sum += __shfl_xor(sum, off, 64);
          ss  += __shfl_xor(ss, off, 64);
        }
        const float mu = sum * (1.f / 64.f);
        const float var = ss * (1.f / 64.f) - mu * mu;
        const float rstd = 1.f / sqrtf(var + 1e-5f);
        float y[4];
        y[0] = (x.x - mu) * rstd * lngv.x + lnbv.x;
        y[1] = (x.y - mu) * rstd * lngv.y + lnbv.y;
        y[2] = (x.z - mu) * rstd * lngv.z + lnbv.z;
        y[3] = (x.w - mu) * rstd * lngv.w + lnbv.w;
        uint2 p;
        p.x = (uint32_t)f2bf(y[0]) | ((uint32_t)f2bf(y[1]) << 16);
        p.y = (uint32_t)f2bf(y[2]) | ((uint32_t)f2bf(y[3]) << 16);
        *(uint2*)&mA[(si * 4 + rl) * 72 + c4 * 4] = p;
        const float m = mv[si];
        qacc[0] += m * y[0]; qacc[1] += m * y[1];
        qacc[2] += m * y[2]; qacc[3] += m * y[3];
        cacc += m;
      }
      const short8 a0 = *(const short8*)&mA[c4 * 72 + rl * 8];
      const short8 a1 = *(const short8*)&mA[c4 * 72 + 32 + rl * 8];
      floatx4 c = {0.f, 0.f, 0.f, 0.f};
      c = __builtin_amdgcn_mfma_f32_16x16x32_bf16(a0, b0, c, 0, 0, 0);
      c = __builtin_amdgcn_mfma_f32_16x16x32_bf16(a1, b1, c, 0, 0, 0);
#pragma unroll
      for (int i = 0; i < 4; ++i)  // C/D: row = rl*4+i -> si=rl, r_off=i; col n=c4
        kS[i * 1024 + (grp * 4 + rl) * 16 + c4] = f2bf(c[i]);
    }

    // kv dump: per r, 64 s x 32B = 2KB contiguous
#pragma unroll
    for (int i = 0; i < 4; ++i) {
#pragma unroll
      for (int t = 0; t < 2; ++t) {
        const uint4 val = *(const uint4*)&kS[i * 1024 + t * 512 + lane * 8];
        *(uint4*)(kv + ((size_t)(r0w + i) * S_DIM + s0) * 16 + t * 512 + lane * 8) = val;
      }
    }
    *(float4*)&qpart[((size_t)(r0w + rl) * NCH + sc) * 72 + c4 * 4] =
        make_float4(qacc[0], qacc[1], qacc[2], qacc[3]);
    if (c4 == 0)
      qpart[((size_t)(r0w + rl) * NCH + sc) * 72 + 64] = cacc;
  }

  __threadfence();
  grid.sync();

  // ---------------- Phase 2: q, logits, softmax, o (blocks flat < 384) ----------------
  {
    const int flat = blockIdx.y * NCH + blockIdx.x;
    if (flat < R_DIM) {
      const int r = flat;
      float* qavgL  = (float*)smem;        // 64
      float* qLs    = (float*)smem + 64;   // 64
      float* redmax = (float*)smem + 128;  // [4][8]
      float* redden = (float*)smem + 160;  // [4][8]
      float* redo_  = (float*)smem + 192;  // [4][64]
      float* cntL   = (float*)smem + 448;  // 1
      const int wv = w;

      float qs = 0.f;
      if (tid < 65) {
#pragma unroll
        for (int c = 0; c < NCH; ++c) qs += qpart[((size_t)r * NCH + c) * 72 + tid];
        if (tid == 64) *cntL = qs;
      }
      __syncthreads();
      if (tid < 64) qavgL[tid] = qs / (*cntL + 1e-10f);
      __syncthreads();
      if (tid < 64) {
        float a = 0.f;
        for (int d = 0; d < 64; ++d) a += qavgL[d] * Wq[d * 64 + tid];
        qLs[tid] = a * 0.35355339059327373f;  // C^-0.5
      }
      __syncthreads();

      const uint4* kvp = (const uint4*)kv;
#pragma unroll
      for (int hg = 0; hg < 2; ++hg) {
        float l[32], lm[4];
#pragma unroll
        for (int h4 = 0; h4 < 4; ++h4) lm[h4] = -3.0e38f;
#pragma unroll
        for (int it = 0; it < 8; ++it) {
          const int s = it * 256 + tid;
          uint4 kw = kvp[((size_t)r * S_DIM + s) * 2];
          float k[8]; unpack8(kw, k);
          const float bias = (mask[(size_t)s * R_DIM + r] - 1.f) * 1e9f;
#pragma unroll
          for (int h4 = 0; h4 < 4; ++h4) {
            const int h = hg * 4 + h4;
            float t = bias;
#pragma unroll
            for (int c = 0; c < 8; ++c) t += qLs[h * 8 + c] * k[c];
            l[it * 4 + h4] = t;
            lm[h4] = fmaxf(lm[h4], t);
          }
        }
#pragma unroll
        for (int h4 = 0; h4 < 4; ++h4)
#pragma unroll
          for (int off = 1; off < 64; off <<= 1)
            lm[h4] = fmaxf(lm[h4], __shfl_xor(lm[h4], off, 64));
        if (lane == 0) {
#pragma unroll
          for (int h4 = 0; h4 < 4; ++h4) redmax[wv * 8 + hg * 4 + h4] = lm[h4];
        }
        __syncthreads();
        float gm[4];
#pragma unroll
        for (int h4 = 0; h4 < 4; ++h4)
          gm[h4] = fmaxf(fmaxf(redmax[0 * 8 + hg * 4 + h4], redmax[1 * 8 + hg * 4 + h4]),
                         fmaxf(redmax[2 * 8 + hg * 4 + h4], redmax[3 * 8 + hg * 4 + h4]));

        float den[4] = {0.f, 0.f, 0.f, 0.f};
        float ao[32];
#pragma unroll
        for (int i = 0; i < 32; ++i) ao[i] = 0.f;
#pragma unroll
        for (int it = 0; it < 8; ++it) {
          const int s = it * 256 + tid;
          uint4 vw = kvp[((size_t)r * S_DIM + s) * 2 + 1];
          float v[8]; unpack8(vw, v);
#pragma unroll
          for (int h4 = 0; h4 < 4; ++h4) {
            const float wgt = __expf(l[it * 4 + h4] - gm[h4]);
            den[h4] += wgt;
#pragma unroll
            for (int c = 0; c < 8; ++c) ao[h4 * 8 + c] += wgt * v[c];
          }
        }
        // fold-exchange within 32-lane halves: lane L -> half-sum of entry (L&31)
#pragma unroll
        for (int st = 4; st >= 0; --st) {
          const int dist = 1 << st;
          const bool hi = (lane & dist) != 0;
#pragma unroll
          for (int j = 0; j < (1 << st); ++j) {
            const float send = hi ? ao[j] : ao[j + dist];
            const float recv = __shfl_xor(send, dist, 64);
            ao[j] = (hi ? ao[j + dist] : ao[j]) + recv;
          }
        }
        ao[0] += __shfl_xor(ao[0], 32, 64);  // combine halves
#pragma unroll
        for (int h4 = 0; h4 < 4; ++h4)
#pragma unroll
          for (int off = 1; off < 64; off <<= 1) den[h4] += __shfl_xor(den[h4], off, 64);

        redo_[wv * 64 + hg * 32 + (lane & 31)] = ao[0];
        if (lane == 0) {
#pragma unroll
          for (int h4 = 0; h4 < 4; ++h4) redden[wv * 8 + hg * 4 + h4] = den[h4];
        }
        __syncthreads();
      }
      if (tid < 64) {
        const float o = redo_[0 * 64 + tid] + redo_[1 * 64 + tid] +
                        redo_[2 * 64 + tid] + redo_[3 * 64 + tid];
        const int h = tid >> 3;
        const float dd = redden[0 * 8 + h] + redden[1 * 8 + h] +
                         redden[2 * 8 + h] + redden[3 * 8 + h];
        oG[(size_t)r * 64 + tid] = o / dd;
      }
    }
  }

  __threadfence();
  grid.sync();

  // ---------------- Phase 3: LN -> gate MFMA -> out MFMA -> residual ----------------
  {
    uint16_t* WgT = (uint16_t*)smem;                         // [64][72]
    uint16_t* WoT = (uint16_t*)(smem + 9216);                // [64][72]
    uint16_t* mA  = (uint16_t*)(smem + 18432) + w * 1152;    // per-wave [16][72]
    uint16_t* tAw = (uint16_t*)(smem + 27648) + w * 1152;    // per-wave [16][72]

#pragma unroll
    for (int i = 0; i < 16; ++i) {
      const int idx = i * 256 + tid;        // 4096 weight elems
      const int a = idx >> 6, b = idx & 63;
      WgT[b * 72 + a] = f2bf(Wg[idx]);      // a=d, b=hc
      WoT[b * 72 + a] = f2bf(Wo[idx]);      // a=hc, b=d
    }
    const float4 lngv = ((const float4*)lng)[c4];
    const float4 lnbv = ((const float4*)lnb)[c4];
    __syncthreads();

    short8 wgB[4][2], woB[4][2];
#pragma unroll
    for (int nt = 0; nt < 4; ++nt)
#pragma unroll
      for (int kk = 0; kk < 2; ++kk) {
        wgB[nt][kk] = *(const short8*)&WgT[(nt * 16 + c4) * 72 + kk * 32 + rl * 8];
        woB[nt][kk] = *(const short8*)&WoT[(nt * 16 + c4) * 72 + kk * 32 + rl * 8];
      }
    float og[4][4], bgr[4], bor[4];
#pragma unroll
    for (int nt = 0; nt < 4; ++nt) {
      bgr[nt] = bg[nt * 16 + c4];
      bor[nt] = bo[nt * 16 + c4];
#pragma unroll
      for (int i = 0; i < 4; ++i)
        og[nt][i] = oG[(size_t)(r0w + i) * 64 + nt * 16 + c4];
    }

#pragma unroll 2
    for (int grp = 0; grp < 16; ++grp) {
      const int sg = s0 + grp * 4;
      float4 xg[4];
#pragma unroll
      for (int si = 0; si < 4; ++si)
        xg[si] = ((const float4*)(M + ((size_t)(sg + si) * R_DIM + r0w + rl) * 64))[c4];

#pragma unroll
      for (int si = 0; si < 4; ++si) {
        const float4 x = xg[si];
        float sum = x.x + x.y + x.z + x.w;
        float ss = x.x * x.x + x.y * x.y + x.z * x.z + x.w * x.w;
#pragma unroll
        for (int off = 1; off < 16; off <<= 1) {
          sum += __shfl_xor(sum, off, 64);
          ss  += __shfl_xor(ss, off, 64);
        }
        const float mu = sum * (1.f / 64.f);
        const float var = ss * (1.f / 64.f) - mu * mu;
        const float rstd = 1.f / sqrtf(var + 1e-5f);
        float y[4];
        y[0] = (x.x - mu) * rstd * lngv.x + lnbv.x;
        y[1] = (x.y - mu) * rstd * lngv.y + lnbv.y;
        y[2] = (x.z - mu) * rstd * lngv.z + lnbv.z;
        y[3] = (x.w - mu) * rstd * lngv.w + lnbv.w;
        uint2 p;
        p.x = (uint32_t)f2bf(y[0]) | ((uint32_t)f2bf(y[1]) << 16);
        p.y = (uint32_t)f2bf(y[2]) | ((uint32_t)f2bf(y[3]) << 16);
        *(uint2*)&mA[(si * 4 + rl) * 72 + c4 * 4] = p;
      }

      // GEMM1: G = mln @ Wg; T = sigmoid(G+bg)*o
      {
        const short8 a0 = *(const short8*)&mA[c4 * 72 + rl * 8];
        const short8 a1 = *(const short8*)&mA[c4 * 72 + 32 + rl * 8];
#pragma unroll
        for (int nt = 0; nt < 4; ++nt) {
          floatx4 c = {0.f, 0.f, 0.f, 0.f};
          c = __builtin_amdgcn_mfma_f32_16x16x32_bf16(a0, wgB[nt][0], c, 0, 0, 0);
          c = __builtin_amdgcn_mfma_f32_16x16x32_bf16(a1, wgB[nt][1], c, 0, 0, 0);
#pragma unroll
          for (int i = 0; i < 4; ++i) {
            const float z = c[i] + bgr[nt];
            const float gt = 1.0f / (1.0f + __expf(-z));
            tAw[(rl * 4 + i) * 72 + nt * 16 + c4] = f2bf(gt * og[nt][i]);
          }
        }
      }
      // GEMM2: OUT = T @ Wo + bo
      {
        const short8 a0 = *(const short8*)&tAw[c4 * 72 + rl * 8];
        const short8 a1 = *(const short8*)&tAw[c4 * 72 + 32 + rl * 8];
#pragma unroll
        for (int nt = 0; nt < 4; ++nt) {
          floatx4 c = {0.f, 0.f, 0.f, 0.f};
          c = __builtin_amdgcn_mfma_f32_16x16x32_bf16(a0, woB[nt][0], c, 0, 0, 0);
          c = __builtin_amdgcn_mfma_f32_16x16x32_bf16(a1, woB[nt][1], c, 0, 0, 0);
#pragma unroll
          for (int i = 0; i < 4; ++i)
            mA[(rl * 4 + i) * 72 + nt * 16 + c4] = f2bf(c[i] + bor[nt]);
        }
      }
      // residual + coalesced store
#pragma unroll
      for (int si = 0; si < 4; ++si) {
        const uint2 tv = *(const uint2*)&mA[(si * 4 + rl) * 72 + c4 * 4];
        const float4 x = xg[si];
        float4 o;
        o.x = x.x + bf2f(tv.x & 0xffff);
        o.y = x.y + bf2f(tv.x >> 16);
        o.z = x.z + bf2f(tv.y & 0xffff);
        o.w = x.w + bf2f(tv.y >> 16);
        ((float4*)(out + ((size_t)(sg + si) * R_DIM + r0w + rl) * 64))[c4] = o;
      }
    }
  }
}

// ============================ fallback: round-1 three-kernel path ============================
__global__ __launch_bounds__(256) void k1_ln_kv(
    const float* __restrict__ M, const float* __restrict__ mask,
    const float* __restrict__ lng, const float* __restrict__ lnb,
    const float* __restrict__ Wk, const float* __restrict__ Wv,
    uint16_t* __restrict__ kv, float* __restrict__ qpart)
{
  __shared__ uint16_t WkvT[16 * 72];
  __shared__ uint16_t mlnA[4][16 * 72];
  __shared__ uint16_t kvS[4][4 * 64 * 16];

  const int tid = threadIdx.x;
  const int w = tid >> 6, lane = tid & 63;
  const int rl = lane >> 4, c4 = lane & 15;
  const int sc = blockIdx.x;
  const int s0 = sc * 64;
  const int r0w = blockIdx.y * 16 + w * 4;

#pragma unroll
  for (int i = 0; i < 4; ++i) {
    const int e = i * 256 + tid;
    const int n = e >> 6, d = e & 63;
    const float val = (n < 8) ? Wk[d * 8 + n] : Wv[d * 8 + (n - 8)];
    WkvT[n * 72 + d] = f2bf(val);
  }
  const float4 lngv = ((const float4*)lng)[c4];
  const float4 lnbv = ((const float4*)lnb)[c4];
  __syncthreads();

  const short8 b0 = *(const short8*)&WkvT[c4 * 72 + rl * 8];
  const short8 b1 = *(const short8*)&WkvT[c4 * 72 + 32 + rl * 8];
  uint16_t* mA = mlnA[w];
  uint16_t* kS = kvS[w];
  float qacc[4] = {0.f, 0.f, 0.f, 0.f};
  float cacc = 0.f;

#pragma unroll 2
  for (int grp = 0; grp < 16; ++grp) {
    const int sg = s0 + grp * 4;
    float4 xg[4];
    float mv[4];
#pragma unroll
    for (int si = 0; si < 4; ++si) {
      const size_t grow = (size_t)(sg + si) * R_DIM + r0w + rl;
      xg[si] = ((const float4*)(M + grow * 64))[c4];
      mv[si] = mask[grow];
    }
#pragma unroll
    for (int si = 0; si < 4; ++si) {
      const float4 x = xg[si];
      float sum = x.x + x.y + x.z + x.w;
      float ss = x.x * x.x + x.y * x.y + x.z * x.z + x.w * x.w;
#pragma unroll
      for (int off = 1; off < 16; off <<= 1) {
        sum += __shfl_xor(sum, off, 64);
        ss  += __shfl_xor(ss, off, 64);
      }
      const float mu = sum * (1.f / 64.f);
      const float var = ss * (1.f / 64.f) - mu * mu;
      const float rstd = 1.f / sqrtf(var + 1e-5f);
      float y[4];
      y[0] = (x.x - mu) * rstd * lngv.x + lnbv.x;
      y[1] = (x.y - mu) * rstd * lngv.y + lnbv.y;
      y[2] = (x.z - mu) * rstd * lngv.z + lnbv.z;
      y[3] = (x.w - mu) * rstd * lngv.w + lnbv.w;
      uint2 p;
      p.x = (uint32_t)f2bf(y[0]) | ((uint32_t)f2bf(y[1]) << 16);
      p.y = (uint32_t)f2bf(y[2]) | ((uint32_t)f2bf(y[3]) << 16);
      *(uint2*)&mA[(si * 4 + rl) * 72 + c4 * 4] = p;
      const float m = mv[si];
      qacc[0] += m * y[0]; qacc[1] += m * y[1];
      qacc[2] += m * y[2]; qacc[3] += m * y[3];
      cacc += m;
    }
    const short8 a0 = *(const short8*)&mA[c4 * 72 + rl * 8];
    const short8 a1 = *(const short8*)&mA[c4 * 72 + 32 + rl * 8];
    floatx4 c = {0.f, 0.f, 0.f, 0.f};
    c = __builtin_amdgcn_mfma_f32_16x16x32_bf16(a0, b0, c, 0, 0, 0);
    c = __builtin_amdgcn_mfma_f32_16x16x32_bf16(a1, b1, c, 0, 0, 0);
#pragma unroll
    for (int i = 0; i < 4; ++i)
      kS[i * 1024 + (grp * 4 + rl) * 16 + c4] = f2bf(c[i]);
  }

#pragma unroll
  for (int i = 0; i < 4; ++i) {
#pragma unroll
    for (int t = 0; t < 2; ++t) {
      const uint4 val = *(const uint4*)&kS[i * 1024 + t * 512 + lane * 8];
      *(uint4*)(kv + ((size_t)(r0w + i) * S_DIM + s0) * 16 + t * 512 + lane * 8) = val;
    }
  }
  *(float4*)&qpart[((size_t)(r0w + rl) * NCH + sc) * 72 + c4 * 4] =
      make_float4(qacc[0], qacc[1], qacc[2], qacc[3]);
  if (c4 == 0)
    qpart[((size_t)(r0w + rl) * NCH + sc) * 72 + 64] = cacc;
}

__global__ __launch_bounds__(256) void k2_attn(
    const float* __restrict__ Wq, const float* __restrict__ mask,
    const uint16_t* __restrict__ kv, const float* __restrict__ qpart,
    float* __restrict__ oG)
{
  __shared__ float qavgL[64], qLs[64];
  __shared__ float redmax[4][8], redden[4][8], redo[4][64];
  __shared__ float cntL;
  const int tid = threadIdx.x;
  const int r = blockIdx.x;
  const int lane = tid & 63, wv = tid >> 6;

  float qs = 0.f;
  if (tid < 65) {
#pragma unroll
    for (int c = 0; c < NCH; ++c) qs += qpart[((size_t)r * NCH + c) * 72 + tid];
    if (tid == 64) cntL = qs;
  }
  __syncthreads();
  if (tid < 64) qavgL[tid] = qs / (cntL + 1e-10f);
  __syncthreads();
  if (tid < 64) {
    float a = 0.f;
    for (int d = 0; d < 64; ++d) a += qavgL[d] * Wq[d * 64 + tid];
    qLs[tid] = a * 0.35355339059327373f;
  }
  __syncthreads();

  float l[64];
  float lm[8];
#pragma unroll
  for (int h = 0; h < 8; ++h) lm[h] = -3.0e38f;
  const uint4* kvp = (const uint4*)kv;
#pragma unroll
  for (int it = 0; it < 8; ++it) {
    const int s = it * 256 + tid;
    uint4 kw = kvp[((size_t)r * S_DIM + s) * 2];
    float k[8]; unpack8(kw, k);
    const float bias = (mask[(size_t)s * R_DIM + r] - 1.f) * 1e9f;
#pragma unroll
    for (int h = 0; h < 8; ++h) {
      float t = bias;
#pragma unroll
      for (int c = 0; c < 8; ++c) t += qLs[h * 8 + c] * k[c];
      l[it * 8 + h] = t;
      lm[h] = fmaxf(lm[h], t);
    }
  }
#pragma unroll
  for (int h = 0; h < 8; ++h)
#pragma unroll
    for (int off = 1; off < 64; off <<= 1) lm[h] = fmaxf(lm[h], __shfl_xor(lm[h], off, 64));
  if (lane == 0) {
#pragma unroll
    for (int h = 0; h < 8; ++h) redmax[wv][h] = lm[h];
  }
  __syncthreads();
  float gm[8];
#pragma unroll
  for (int h = 0; h < 8; ++h)
    gm[h] = fmaxf(fmaxf(redmax[0][h], redmax[1][h]), fmaxf(redmax[2][h], redmax[3][h]));

  float den[8], ao[64];
#pragma unroll
  for (int h = 0; h < 8; ++h) den[h] = 0.f;
#pragma unroll
  for (int i = 0; i < 64; ++i) ao[i] = 0.f;
#pragma unroll
  for (int it = 0; it < 8; ++it) {
    const int s = it * 256 + tid;
    uint4 vw = kvp[((size_t)r * S_DIM + s) * 2 + 1];
    float v[8]; unpack8(vw, v);
#pragma unroll
    for (int h = 0; h < 8; ++h) {
      const float w = __expf(l[it * 8 + h] - gm[h]);
      den[h] += w;
#pragma unroll
      for (int c = 0; c < 8; ++c) ao[h * 8 + c] += w * v[c];
    }
  }
#pragma unroll
  for (int st = 5; st >= 0; --st) {
    const int dist = 1 << st;
    const bool hi = (lane & dist) != 0;
#pragma unroll
    for (int j = 0; j < (1 << st); ++j) {
      const float send = hi ? ao[j] : ao[j + dist];
      const float recv = __shfl_xor(send, dist, 64);
      ao[j] = (hi ? ao[j + dist] : ao[j]) + recv;
    }
  }
#pragma unroll
  for (int h = 0; h < 8; ++h)
#pragma unroll
    for (int off = 1; off < 64; off <<= 1) den[h] += __shfl_xor(den[h], off, 64);

  redo[wv][lane] = ao[0];
  if (lane == 0) {
#pragma unroll
    for (int h = 0; h < 8; ++h) redden[wv][h] = den[h];
  }
  __syncthreads();
  if (tid < 64) {
    const float o = redo[0][tid] + redo[1][tid] + redo[2][tid] + redo[3][tid];
    const int h = tid >> 3;
    const float dd = redden[0][h] + redden[1][h] + redden[2][h] + redden[3][h];
    oG[(size_t)r * 64 + tid] = o / dd;
  }
}

__global__ __launch_bounds__(256, 2) void k3_out(
    const float* __restrict__ M, const float* __restrict__ oG,
    const float* __restrict__ Wg, const float* __restrict__ bg,
    const float* __restrict__ Wo, const float* __restrict__ bo,
    const float* __restrict__ lng, const float* __restrict__ lnb,
    float* __restrict__ out)
{
  __shared__ uint16_t WgT[64 * 72];
  __shared__ uint16_t WoT[64 * 72];
  __shared__ uint16_t mlnA[4][16 * 72];
  __shared__ uint16_t tA[4][16 * 72];

  const int tid = threadIdx.x;
  const int w = tid >> 6, lane = tid & 63;
  const int rl = lane >> 4, c4 = lane & 15;
  const int sc = blockIdx.x;
  const int s0 = sc * 64;
  const int r0w = blockIdx.y * 16 + w * 4;

#pragma unroll
  for (int i = 0; i < 16; ++i) {
    const int idx = i * 256 + tid;
    const int a = idx >> 6, b = idx & 63;
    WgT[b * 72 + a] = f2bf(Wg[idx]);
    WoT[b * 72 + a] = f2bf(Wo[idx]);
  }
  const float4 lngv = ((const float4*)lng)[c4];
  const float4 lnbv = ((const float4*)lnb)[c4];
  __syncthreads();

  short8 wgB[4][2], woB[4][2];
#pragma unroll
  for (int nt = 0; nt < 4; ++nt)
#pragma unroll
    for (int kk = 0; kk < 2; ++kk) {
      wgB[nt][kk] = *(const short8*)&WgT[(nt * 16 + c4) * 72 + kk * 32 + rl * 8];
      woB[nt][kk] = *(const short8*)&WoT[(nt * 16 + c4) * 72 + kk * 32 + rl * 8];
    }
  float og[4][4], bgr[4], bor[4];
#pragma unroll
  for (int nt = 0; nt < 4; ++nt) {
    bgr[nt] = bg[nt * 16 + c4];
    bor[nt] = bo[nt * 16 + c4];
#pragma unroll
    for (int i = 0; i < 4; ++i)
      og[nt][i] = oG[(size_t)(r0w + i) * 64 + nt * 16 + c4];
  }
  uint16_t* mA = mlnA[w];
  uint16_t* tAw = tA[w];

#pragma unroll 2
  for (int grp = 0; grp < 16; ++grp) {
    const int sg = s0 + grp * 4;
    float4 xg[4];
#pragma unroll
    for (int si = 0; si < 4; ++si)
      xg[si] = ((const float4*)(M + ((size_t)(sg + si) * R_DIM + r0w + rl) * 64))[c4];

#pragma unroll
    for (int si = 0; si < 4; ++si) {
      const float4 x = xg[si];
      float sum = x.x + x.y + x.z + x.w;
      float ss = x.x * x.x + x.y * x.y + x.z * x.z + x.w * x.w;
#pragma unroll
      for (int off = 1; off < 16; off <<= 1) {
        sum += __shfl_xor(sum, off, 64);
        ss  += __shfl_xor(ss, off, 64);
      }
      const float mu = sum * (1.f / 64.f);
      const float var = ss * (1.f / 64.f) - mu * mu;
      const float rstd = 1.f / sqrtf(var + 1e-5f);
      float y[4];
      y[0] = (x.x - mu) * rstd * lngv.x + lnbv.x;
      y[1] = (x.y - mu) * rstd * lngv.y + lnbv.y;
      y[2] = (x.z - mu) * rstd * lngv.z + lnbv.z;
      y[3] = (x.w - mu) * rstd * lngv.w + lnbv.w;
      uint2 p;
      p.x = (uint32_t)f2bf(y[0]) | ((uint32_t)f2bf(y[1]) << 16);
      p.y = (uint32_t)f2bf(y[2]) | ((uint32_t)f2bf(y[3]) << 16);
      *(uint2*)&mA[(si * 4 + rl) * 72 + c4 * 4] = p;
    }

    {
      const short8 a0 = *(const short8*)&mA[c4 * 72 + rl * 8];
      const short8 a1 = *(const short8*)&mA[c4 * 72 + 32 + rl * 8];
#pragma unroll
      for (int nt = 0; nt < 4; ++nt) {
        floatx4 c = {0.f, 0.f, 0.f, 0.f};
        c = __builtin_amdgcn_mfma_f32_16x16x32_bf16(a0, wgB[nt][0], c, 0, 0, 0);
        c = __builtin_amdgcn_mfma_f32_16x16x32_bf16(a1, wgB[nt][1], c, 0, 0, 0);
#pragma unroll
        for (int i = 0; i < 4; ++i) {
          const float z = c[i] + bgr[nt];
          const float gt = 1.0f / (1.0f + __expf(-z));
          tAw[(rl * 4 + i) * 72 + nt * 16 + c4] = f2bf(gt * og[nt][i]);
        }
      }
    }
    {
      const short8 a0 = *(const short8*)&tAw[c4 * 72 + rl * 8];
      const short8 a1 = *(const short8*)&tAw[c4 * 72 + 32 + rl * 8];
#pragma unroll
      for (int nt = 0; nt < 4; ++nt) {
        floatx4 c = {0.f, 0.f, 0.f, 0.f};
        c = __builtin_amdgcn_mfma_f32_16x16x32_bf16(a0, woB[nt][0], c, 0, 0, 0);
        c = __builtin_amdgcn_mfma_f32_16x16x32_bf16(a1, woB[nt][1], c, 0, 0, 0);
#pragma unroll
        for (int i = 0; i < 4; ++i)
          mA[(rl * 4 + i) * 72 + nt * 16 + c4] = f2bf(c[i] + bor[nt]);
      }
    }
#pragma unroll
    for (int si = 0; si < 4; ++si) {
      const uint2 tv = *(const uint2*)&mA[(si * 4 + rl) * 72 + c4 * 4];
      const float4 x = xg[si];
      float4 o;
      o.x = x.x + bf2f(tv.x & 0xffff);
      o.y = x.y + bf2f(tv.x >> 16);
      o.z = x.z + bf2f(tv.y & 0xffff);
      o.w = x.w + bf2f(tv.y >> 16);
      ((float4*)(out + ((size_t)(sg + si) * R_DIM + r0w + rl) * 64))[c4] = o;
    }
  }
}

extern "C" void kernel_launch(void* const* d_in, const int* in_sizes, int n_in,
                              void* d_out, int out_size, void* d_ws, size_t ws_size,
                              hipStream_t stream)
{
  const float* M    = (const float*)d_in[0];
  const float* mask = (const float*)d_in[1];
  const float* lng  = (const float*)d_in[2];
  const float* lnb  = (const float*)d_in[3];
  const float* Wq   = (const float*)d_in[4];
  const float* Wk   = (const float*)d_in[5];
  const float* Wv   = (const float*)d_in[6];
  const float* Wg   = (const float*)d_in[7];
  const float* bg   = (const float*)d_in[8];
  const float* Wo   = (const float*)d_in[9];
  const float* bo   = (const float*)d_in[10];
  float* out = (float*)d_out;

  char* ws = (char*)d_ws;
  uint16_t* kvB  = (uint16_t*)(ws + KV_OFF);
  float* qpartB  = (float*)(ws + QPART_OFF);
  float* oB      = (float*)(ws + O_OFF);

  static int coop_ok = -1;
  if (coop_ok < 0) {
    int v = 0;
    if (hipDeviceGetAttribute(&v, hipDeviceAttributeCooperativeLaunch, 0) != hipSuccess) v = 0;
    coop_ok = v;
  }

  bool launched = false;
  if (coop_ok > 0) {
    void* args[] = {(void*)&M, (void*)&mask, (void*)&lng, (void*)&lnb,
                    (void*)&Wq, (void*)&Wk, (void*)&Wv, (void*)&Wg,
                    (void*)&bg, (void*)&Wo, (void*)&bo, (void*)&out,
                    (void*)&kvB, (void*)&qpartB, (void*)&oB};
    hipError_t e = hipLaunchCooperativeKernel((const void*)fused_all, dim3(NCH, 24),
                                              dim3(256, 1, 1), args, 0, stream);
    launched = (e == hipSuccess);
  }
  if (!launched) {
    k1_ln_kv<<<dim3(NCH, 24), 256, 0, stream>>>(M, mask, lng, lnb, Wk, Wv, kvB, qpartB);
    k2_attn<<<dim3(R_DIM), 256, 0, stream>>>(Wq, mask, kvB, qpartB, oB);
    k3_out<<<dim3(NCH, 24), 256, 0, stream>>>(M, oB, Wg, bg, Wo, bo, lng, lnb, out);
  }
}

// Round 4
// 453.378 us; speedup vs baseline: 1.9475x; 1.9475x over previous
//
#include <hip/hip_runtime.h>
#include <hip/hip_bf16.h>
#include <stdint.h>

// MSAColumnGlobalAttention: B=1, S=2048, R=384, D=64, H=8, C=8, HC=64
// v5 (resubmit; round-3 bench was an infra failure, no counters returned).
// Round-1 three-kernel structure (cooperative fusion refuted in round 2:
// grid.sync spin + half-width phase2 = 632us stall-dominated kernel).
// Changes vs round-1:
//  - HW bf16 converts (v_cvt_pk_bf16_f32 via __float22bfloat162_rn) replace
//    the ~5-op manual RNE pack (same rounding -> bit-identical output).
//  - k1: kv staged per 16-s block (kvS 32KB->8KB, LDS 44.3->19.7KB) ->
//    launch_bounds(256,4) = 4 blocks/CU; explicit next-group M/mask prefetch.
//  - k3: launch_bounds(256,3) (LDS 36.9KB permits 4 blocks/CU).

#define DEV __device__ __forceinline__

typedef __attribute__((ext_vector_type(8))) short short8;   // 8 bf16 (4 VGPRs) MFMA A/B frag
typedef __attribute__((ext_vector_type(4))) float floatx4;  // MFMA C/D frag

static constexpr int S_DIM = 2048;
static constexpr int R_DIM = 384;
static constexpr int NCH   = 32;    // s-chunks of 64

// ws layout (bytes)
static constexpr size_t KV_OFF    = 0;         // bf16 [384][2048][16] (k0..7, v0..7) = 25165824
static constexpr size_t QPART_OFF = 25165824;  // f32  [384][32][72]  (64 q sums + cnt) = 3538944
static constexpr size_t O_OFF     = 28704768;  // f32  [384][64]

DEV float bf2f(uint32_t u) { union { uint32_t i; float f; } c; c.i = u << 16; return c.f; }
DEV uint32_t pk2bf(float lo, float hi) {  // -> v_cvt_pk_bf16_f32 (RNE)
  __hip_bfloat162 h2 = __float22bfloat162_rn(make_float2(lo, hi));
  union { __hip_bfloat162 h; uint32_t u; } cv; cv.h = h2; return cv.u;
}
DEV uint16_t f2bf_hw(float f) {  // scalar cast -> HW convert (RNE)
  __hip_bfloat16 h = __float2bfloat16(f);
  union { __hip_bfloat16 h; uint16_t u; } cv; cv.h = h; return cv.u;
}
DEV void unpack8(uint4 w, float* x) {
  x[0] = bf2f(w.x & 0xffff); x[1] = bf2f(w.x >> 16);
  x[2] = bf2f(w.y & 0xffff); x[3] = bf2f(w.y >> 16);
  x[4] = bf2f(w.z & 0xffff); x[5] = bf2f(w.z >> 16);
  x[6] = bf2f(w.w & 0xffff); x[7] = bf2f(w.w >> 16);
}

// ---------------- K1: LN + kv (MFMA) + masked-q partials ----------------
// grid (32 s-chunks, 24 r-chunks), block 256. Wave w owns r0w = rc*16+w*4 (4 r)
// across the chunk's 64 s. Lane: rl = lane>>4 (r offset), c4 = lane&15 (d quad).
__global__ __launch_bounds__(256, 4) void k1_ln_kv(
    const float* __restrict__ M, const float* __restrict__ mask,
    const float* __restrict__ lng, const float* __restrict__ lnb,
    const float* __restrict__ Wk, const float* __restrict__ Wv,
    uint16_t* __restrict__ kv, float* __restrict__ qpart)
{
  __shared__ uint16_t WkvT[16 * 72];    // 2304 B: B operand [n=c(0..7 k, 8..15 v)][k=d]
  __shared__ uint16_t mlnA[4][16 * 72]; // 9216 B: per-wave A staging [row=si*4+rl][d]
  __shared__ uint16_t kvS[4][1024];     // 8192 B: per-wave kv staging [r4][s16][c16]

  const int tid = threadIdx.x;
  const int w = tid >> 6, lane = tid & 63;
  const int rl = lane >> 4, c4 = lane & 15;
  const int sc = blockIdx.x;
  const int s0 = sc * 64;
  const int r0w = blockIdx.y * 16 + w * 4;

#pragma unroll
  for (int i = 0; i < 4; ++i) {
    const int e = i * 256 + tid;         // 1024 elems
    const int n = e >> 6, d = e & 63;
    const float val = (n < 8) ? Wk[d * 8 + n] : Wv[d * 8 + (n - 8)];
    WkvT[n * 72 + d] = f2bf_hw(val);
  }
  const float4 lngv = ((const float4*)lng)[c4];
  const float4 lnbv = ((const float4*)lnb)[c4];
  __syncthreads();

  // B fragments: B[n = c4][k = rl*8 + j (+32)]
  const short8 b0 = *(const short8*)&WkvT[c4 * 72 + rl * 8];
  const short8 b1 = *(const short8*)&WkvT[c4 * 72 + 32 + rl * 8];

  uint16_t* mA = mlnA[w];
  uint16_t* kS = kvS[w];

  float qacc[4] = {0.f, 0.f, 0.f, 0.f};
  float cacc = 0.f;

  // prime group 0 (1KB contiguous per wave instruction)
  float4 xg[4];
  float mv[4];
#pragma unroll
  for (int si = 0; si < 4; ++si) {
    const size_t grow = (size_t)(s0 + si) * R_DIM + r0w + rl;
    xg[si] = ((const float4*)(M + grow * 64))[c4];
    mv[si] = mask[grow];
  }

#pragma unroll 2
  for (int grp = 0; grp < 16; ++grp) {
    // prefetch next group while this one is processed (latency cover)
    const int gn = (grp < 15) ? grp + 1 : 15;
    float4 xn[4];
    float mn[4];
#pragma unroll
    for (int si = 0; si < 4; ++si) {
      const size_t grow = (size_t)(s0 + gn * 4 + si) * R_DIM + r0w + rl;
      xn[si] = ((const float4*)(M + grow * 64))[c4];
      mn[si] = mask[grow];
    }

#pragma unroll
    for (int si = 0; si < 4; ++si) {
      const float4 x = xg[si];
      float sum = x.x + x.y + x.z + x.w;
      float ss = x.x * x.x + x.y * x.y + x.z * x.z + x.w * x.w;
#pragma unroll
      for (int off = 1; off < 16; off <<= 1) {
        sum += __shfl_xor(sum, off, 64);
        ss  += __shfl_xor(ss, off, 64);
      }
      const float mu = sum * (1.f / 64.f);
      const float var = ss * (1.f / 64.f) - mu * mu;
      const float rstd = 1.f / sqrtf(var + 1e-5f);
      float y[4];
      y[0] = (x.x - mu) * rstd * lngv.x + lnbv.x;
      y[1] = (x.y - mu) * rstd * lngv.y + lnbv.y;
      y[2] = (x.z - mu) * rstd * lngv.z + lnbv.z;
      y[3] = (x.w - mu) * rstd * lngv.w + lnbv.w;
      uint2 p;
      p.x = pk2bf(y[0], y[1]);
      p.y = pk2bf(y[2], y[3]);
      *(uint2*)&mA[(si * 4 + rl) * 72 + c4 * 4] = p;
      const float m = mv[si];
      qacc[0] += m * y[0]; qacc[1] += m * y[1];
      qacc[2] += m * y[2]; qacc[3] += m * y[3];
      cacc += m;
    }
    // MFMA: A[row = si*4 + r_off][k=d]; lane reads row=c4, kslice=rl*8.
    const short8 a0 = *(const short8*)&mA[c4 * 72 + rl * 8];
    const short8 a1 = *(const short8*)&mA[c4 * 72 + 32 + rl * 8];
    floatx4 c = {0.f, 0.f, 0.f, 0.f};
    c = __builtin_amdgcn_mfma_f32_16x16x32_bf16(a0, b0, c, 0, 0, 0);
    c = __builtin_amdgcn_mfma_f32_16x16x32_bf16(a1, b1, c, 0, 0, 0);
    // C/D: row = rl*4 + i -> si = rl, r_off = i; col n = c4.
#pragma unroll
    for (int i = 0; i < 4; ++i)
      kS[i * 256 + ((grp & 3) * 4 + rl) * 16 + c4] = f2bf_hw(c[i]);

    // dump a completed 16-s block: per (r,t) 16 lanes x 8B = 128B dense
    if ((grp & 3) == 3) {
      const int sb = grp >> 2;
      const int rI = lane >> 4, li = lane & 15;
#pragma unroll
      for (int t = 0; t < 4; ++t) {
        const uint2 val = *(const uint2*)&kS[rI * 256 + t * 64 + li * 4];
        *(uint2*)(kv + ((size_t)(r0w + rI) * S_DIM + s0 + sb * 16) * 16 + t * 64 + li * 4) = val;
      }
    }
#pragma unroll
    for (int si = 0; si < 4; ++si) { xg[si] = xn[si]; mv[si] = mn[si]; }
  }

  // q partials: lane owns (r = r0w+rl, d = c4*4..+3) summed over this chunk
  *(float4*)&qpart[((size_t)(r0w + rl) * NCH + sc) * 72 + c4 * 4] =
      make_float4(qacc[0], qacc[1], qacc[2], qacc[3]);
  if (c4 == 0)
    qpart[((size_t)(r0w + rl) * NCH + sc) * 72 + 64] = cacc;
}

// ---------------- K2: q, logits, softmax, o ----------------
__global__ __launch_bounds__(256) void k2_attn(
    const float* __restrict__ Wq, const float* __restrict__ mask,
    const uint16_t* __restrict__ kv, const float* __restrict__ qpart,
    float* __restrict__ oG)
{
  __shared__ float qavgL[64], qLs[64];
  __shared__ float redmax[4][8], redden[4][8], redo[4][64];
  __shared__ float cntL;
  const int tid = threadIdx.x;
  const int r = blockIdx.x;
  const int lane = tid & 63, wv = tid >> 6;

  float qs = 0.f;
  if (tid < 65) {
#pragma unroll
    for (int c = 0; c < NCH; ++c) qs += qpart[((size_t)r * NCH + c) * 72 + tid];
    if (tid == 64) cntL = qs;
  }
  __syncthreads();
  if (tid < 64) qavgL[tid] = qs / (cntL + 1e-10f);
  __syncthreads();
  if (tid < 64) {
    float a = 0.f;
    for (int d = 0; d < 64; ++d) a += qavgL[d] * Wq[d * 64 + tid];
    qLs[tid] = a * 0.35355339059327373f;  // C^-0.5
  }
  __syncthreads();

  float l[64];
  float lm[8];
#pragma unroll
  for (int h = 0; h < 8; ++h) lm[h] = -3.0e38f;
  const uint4* kvp = (const uint4*)kv;
#pragma unroll
  for (int it = 0; it < 8; ++it) {
    const int s = it * 256 + tid;
    uint4 kw = kvp[((size_t)r * S_DIM + s) * 2];
    float k[8]; unpack8(kw, k);
    const float bias = (mask[(size_t)s * R_DIM + r] - 1.f) * 1e9f;
#pragma unroll
    for (int h = 0; h < 8; ++h) {
      float t = bias;
#pragma unroll
      for (int c = 0; c < 8; ++c) t += qLs[h * 8 + c] * k[c];
      l[it * 8 + h] = t;
      lm[h] = fmaxf(lm[h], t);
    }
  }
#pragma unroll
  for (int h = 0; h < 8; ++h)
#pragma unroll
    for (int off = 1; off < 64; off <<= 1) lm[h] = fmaxf(lm[h], __shfl_xor(lm[h], off, 64));
  if (lane == 0) {
#pragma unroll
    for (int h = 0; h < 8; ++h) redmax[wv][h] = lm[h];
  }
  __syncthreads();
  float gm[8];
#pragma unroll
  for (int h = 0; h < 8; ++h)
    gm[h] = fmaxf(fmaxf(redmax[0][h], redmax[1][h]), fmaxf(redmax[2][h], redmax[3][h]));

  float den[8], ao[64];
#pragma unroll
  for (int h = 0; h < 8; ++h) den[h] = 0.f;
#pragma unroll
  for (int i = 0; i < 64; ++i) ao[i] = 0.f;
#pragma unroll
  for (int it = 0; it < 8; ++it) {
    const int s = it * 256 + tid;
    uint4 vw = kvp[((size_t)r * S_DIM + s) * 2 + 1];
    float v[8]; unpack8(vw, v);
#pragma unroll
    for (int h = 0; h < 8; ++h) {
      const float w = __expf(l[it * 8 + h] - gm[h]);
      den[h] += w;
#pragma unroll
      for (int c = 0; c < 8; ++c) ao[h * 8 + c] += w * v[c];
    }
  }
  // fold-exchange ao: lane L ends with the wave sum for hc=L in ao[0]
#pragma unroll
  for (int st = 5; st >= 0; --st) {
    const int dist = 1 << st;
    const bool hi = (lane & dist) != 0;
#pragma unroll
    for (int j = 0; j < (1 << st); ++j) {
      const float send = hi ? ao[j] : ao[j + dist];
      const float recv = __shfl_xor(send, dist, 64);
      ao[j] = (hi ? ao[j + dist] : ao[j]) + recv;
    }
  }
#pragma unroll
  for (int h = 0; h < 8; ++h)
#pragma unroll
    for (int off = 1; off < 64; off <<= 1) den[h] += __shfl_xor(den[h], off, 64);

  redo[wv][lane] = ao[0];
  if (lane == 0) {
#pragma unroll
    for (int h = 0; h < 8; ++h) redden[wv][h] = den[h];
  }
  __syncthreads();
  if (tid < 64) {
    const float o = redo[0][tid] + redo[1][tid] + redo[2][tid] + redo[3][tid];
    const int h = tid >> 3;
    const float dd = redden[0][h] + redden[1][h] + redden[2][h] + redden[3][h];
    oG[(size_t)r * 64 + tid] = o / dd;
  }
}

// ---------------- K3: streaming LN -> gate MFMA -> out MFMA -> residual ----------------
// Same tiling as K1. Per 4-s group: load x (kept in regs), LN (recomputed,
// bit-identical tree), GEMM1+sigmoid gate, GEMM2, residual + 1KB coalesced store.
// No barriers in the loop: all LDS staging is per-wave.
__global__ __launch_bounds__(256, 3) void k3_out(
    const float* __restrict__ M, const float* __restrict__ oG,
    const float* __restrict__ Wg, const float* __restrict__ bg,
    const float* __restrict__ Wo, const float* __restrict__ bo,
    const float* __restrict__ lng, const float* __restrict__ lnb,
    float* __restrict__ out)
{
  __shared__ uint16_t WgT[64 * 72];     // WgT[hc][d] = Wg[d][hc]
  __shared__ uint16_t WoT[64 * 72];     // WoT[d][hc] = Wo[hc][d]
  __shared__ uint16_t mlnA[4][16 * 72]; // per-wave: mln A staging, reused for OUT
  __shared__ uint16_t tA[4][16 * 72];   // per-wave: gated T staging

  const int tid = threadIdx.x;
  const int w = tid >> 6, lane = tid & 63;
  const int rl = lane >> 4, c4 = lane & 15;
  const int sc = blockIdx.x;
  const int s0 = sc * 64;
  const int r0w = blockIdx.y * 16 + w * 4;

#pragma unroll
  for (int i = 0; i < 16; ++i) {
    const int idx = i * 256 + tid;        // 4096 weight elems
    const int a = idx >> 6, b = idx & 63;
    WgT[b * 72 + a] = f2bf_hw(Wg[idx]);   // a=d, b=hc
    WoT[b * 72 + a] = f2bf_hw(Wo[idx]);   // a=hc, b=d
  }
  const float4 lngv = ((const float4*)lng)[c4];
  const float4 lnbv = ((const float4*)lnb)[c4];
  __syncthreads();

  // B fragments: B[n = nt*16+c4][k-slice = kk*32 + rl*8]
  short8 wgB[4][2], woB[4][2];
#pragma unroll
  for (int nt = 0; nt < 4; ++nt)
#pragma unroll
    for (int kk = 0; kk < 2; ++kk) {
      wgB[nt][kk] = *(const short8*)&WgT[(nt * 16 + c4) * 72 + kk * 32 + rl * 8];
      woB[nt][kk] = *(const short8*)&WoT[(nt * 16 + c4) * 72 + kk * 32 + rl * 8];
    }
  float og[4][4], bgr[4], bor[4];
#pragma unroll
  for (int nt = 0; nt < 4; ++nt) {
    bgr[nt] = bg[nt * 16 + c4];
    bor[nt] = bo[nt * 16 + c4];
#pragma unroll
    for (int i = 0; i < 4; ++i)
      og[nt][i] = oG[(size_t)(r0w + i) * 64 + nt * 16 + c4];
  }

  uint16_t* mA = mlnA[w];
  uint16_t* tAw = tA[w];

#pragma unroll 2
  for (int grp = 0; grp < 16; ++grp) {
    const int sg = s0 + grp * 4;
    float4 xg[4];
#pragma unroll
    for (int si = 0; si < 4; ++si)
      xg[si] = ((const float4*)(M + ((size_t)(sg + si) * R_DIM + r0w + rl) * 64))[c4];

#pragma unroll
    for (int si = 0; si < 4; ++si) {
      const float4 x = xg[si];
      float sum = x.x + x.y + x.z + x.w;
      float ss = x.x * x.x + x.y * x.y + x.z * x.z + x.w * x.w;
#pragma unroll
      for (int off = 1; off < 16; off <<= 1) {
        sum += __shfl_xor(sum, off, 64);
        ss  += __shfl_xor(ss, off, 64);
      }
      const float mu = sum * (1.f / 64.f);
      const float var = ss * (1.f / 64.f) - mu * mu;
      const float rstd = 1.f / sqrtf(var + 1e-5f);
      float y[4];
      y[0] = (x.x - mu) * rstd * lngv.x + lnbv.x;
      y[1] = (x.y - mu) * rstd * lngv.y + lnbv.y;
      y[2] = (x.z - mu) * rstd * lngv.z + lnbv.z;
      y[3] = (x.w - mu) * rstd * lngv.w + lnbv.w;
      uint2 p;
      p.x = pk2bf(y[0], y[1]);
      p.y = pk2bf(y[2], y[3]);
      *(uint2*)&mA[(si * 4 + rl) * 72 + c4 * 4] = p;
    }

    // GEMM1: G = mln @ Wg; T = sigmoid(G+bg)*o  (C/D: row = rl*4+i -> si=rl, r_off=i)
    {
      const short8 a0 = *(const short8*)&mA[c4 * 72 + rl * 8];
      const short8 a1 = *(const short8*)&mA[c4 * 72 + 32 + rl * 8];
#pragma unroll
      for (int nt = 0; nt < 4; ++nt) {
        floatx4 c = {0.f, 0.f, 0.f, 0.f};
        c = __builtin_amdgcn_mfma_f32_16x16x32_bf16(a0, wgB[nt][0], c, 0, 0, 0);
        c = __builtin_amdgcn_mfma_f32_16x16x32_bf16(a1, wgB[nt][1], c, 0, 0, 0);
#pragma unroll
        for (int i = 0; i < 4; ++i) {
          const float z = c[i] + bgr[nt];
          const float gt = 1.0f / (1.0f + __expf(-z));
          tAw[(rl * 4 + i) * 72 + nt * 16 + c4] = f2bf_hw(gt * og[nt][i]);
        }
      }
    }
    // GEMM2: OUT = T @ Wo + bo -> mA (reuse)
    {
      const short8 a0 = *(const short8*)&tAw[c4 * 72 + rl * 8];
      const short8 a1 = *(const short8*)&tAw[c4 * 72 + 32 + rl * 8];
#pragma unroll
      for (int nt = 0; nt < 4; ++nt) {
        floatx4 c = {0.f, 0.f, 0.f, 0.f};
        c = __builtin_amdgcn_mfma_f32_16x16x32_bf16(a0, woB[nt][0], c, 0, 0, 0);
        c = __builtin_amdgcn_mfma_f32_16x16x32_bf16(a1, woB[nt][1], c, 0, 0, 0);
#pragma unroll
        for (int i = 0; i < 4; ++i)
          mA[(rl * 4 + i) * 72 + nt * 16 + c4] = f2bf_hw(c[i] + bor[nt]);
      }
    }
    // residual + coalesced store (x from registers; 1KB contiguous per instr)
#pragma unroll
    for (int si = 0; si < 4; ++si) {
      const uint2 tv = *(const uint2*)&mA[(si * 4 + rl) * 72 + c4 * 4];
      const float4 x = xg[si];
      float4 o;
      o.x = x.x + bf2f(tv.x & 0xffff);
      o.y = x.y + bf2f(tv.x >> 16);
      o.z = x.z + bf2f(tv.y & 0xffff);
      o.w = x.w + bf2f(tv.y >> 16);
      ((float4*)(out + ((size_t)(sg + si) * R_DIM + r0w + rl) * 64))[c4] = o;
    }
  }
}

extern "C" void kernel_launch(void* const* d_in, const int* in_sizes, int n_in,
                              void* d_out, int out_size, void* d_ws, size_t ws_size,
                              hipStream_t stream)
{
  const float* M    = (const float*)d_in[0];
  const float* mask = (const float*)d_in[1];
  const float* lng  = (const float*)d_in[2];
  const float* lnb  = (const float*)d_in[3];
  const float* Wq   = (const float*)d_in[4];
  const float* Wk   = (const float*)d_in[5];
  const float* Wv   = (const float*)d_in[6];
  const float* Wg   = (const float*)d_in[7];
  const float* bg   = (const float*)d_in[8];
  const float* Wo   = (const float*)d_in[9];
  const float* bo   = (const float*)d_in[10];
  float* out = (float*)d_out;

  char* ws = (char*)d_ws;
  uint16_t* kvB  = (uint16_t*)(ws + KV_OFF);
  float* qpartB  = (float*)(ws + QPART_OFF);
  float* oB      = (float*)(ws + O_OFF);

  k1_ln_kv<<<dim3(NCH, 24), 256, 0, stream>>>(M, mask, lng, lnb, Wk, Wv, kvB, qpartB);
  k2_attn<<<dim3(R_DIM), 256, 0, stream>>>(Wq, mask, kvB, qpartB, oB);
  k3_out<<<dim3(NCH, 24), 256, 0, stream>>>(M, oB, Wg, bg, Wo, bo, lng, lnb, out);
}

// Round 5
// 436.344 us; speedup vs baseline: 2.0235x; 1.0390x over previous
//
#include <hip/hip_runtime.h>
#include <hip/hip_bf16.h>
#include <stdint.h>

// MSAColumnGlobalAttention: B=1, S=2048, R=384, D=64, H=8, C=8, HC=64
// v6: v5 + (a) k3 gains the same next-group M prefetch k1 has (the 403MB
// stream had its HBM latency fully exposed at the top of each of 16 groups),
// (b) k2 logits loop reads qLs as float4 (4x fewer ds_read ops).

#define DEV __device__ __forceinline__

typedef __attribute__((ext_vector_type(8))) short short8;   // 8 bf16 (4 VGPRs) MFMA A/B frag
typedef __attribute__((ext_vector_type(4))) float floatx4;  // MFMA C/D frag

static constexpr int S_DIM = 2048;
static constexpr int R_DIM = 384;
static constexpr int NCH   = 32;    // s-chunks of 64

// ws layout (bytes)
static constexpr size_t KV_OFF    = 0;         // bf16 [384][2048][16] (k0..7, v0..7) = 25165824
static constexpr size_t QPART_OFF = 25165824;  // f32  [384][32][72]  (64 q sums + cnt) = 3538944
static constexpr size_t O_OFF     = 28704768;  // f32  [384][64]

DEV float bf2f(uint32_t u) { union { uint32_t i; float f; } c; c.i = u << 16; return c.f; }
DEV uint32_t pk2bf(float lo, float hi) {  // -> v_cvt_pk_bf16_f32 (RNE)
  __hip_bfloat162 h2 = __float22bfloat162_rn(make_float2(lo, hi));
  union { __hip_bfloat162 h; uint32_t u; } cv; cv.h = h2; return cv.u;
}
DEV uint16_t f2bf_hw(float f) {  // scalar cast -> HW convert (RNE)
  __hip_bfloat16 h = __float2bfloat16(f);
  union { __hip_bfloat16 h; uint16_t u; } cv; cv.h = h; return cv.u;
}
DEV void unpack8(uint4 w, float* x) {
  x[0] = bf2f(w.x & 0xffff); x[1] = bf2f(w.x >> 16);
  x[2] = bf2f(w.y & 0xffff); x[3] = bf2f(w.y >> 16);
  x[4] = bf2f(w.z & 0xffff); x[5] = bf2f(w.z >> 16);
  x[6] = bf2f(w.w & 0xffff); x[7] = bf2f(w.w >> 16);
}

// ---------------- K1: LN + kv (MFMA) + masked-q partials ----------------
// grid (32 s-chunks, 24 r-chunks), block 256. Wave w owns r0w = rc*16+w*4 (4 r)
// across the chunk's 64 s. Lane: rl = lane>>4 (r offset), c4 = lane&15 (d quad).
__global__ __launch_bounds__(256, 4) void k1_ln_kv(
    const float* __restrict__ M, const float* __restrict__ mask,
    const float* __restrict__ lng, const float* __restrict__ lnb,
    const float* __restrict__ Wk, const float* __restrict__ Wv,
    uint16_t* __restrict__ kv, float* __restrict__ qpart)
{
  __shared__ uint16_t WkvT[16 * 72];    // 2304 B: B operand [n=c(0..7 k, 8..15 v)][k=d]
  __shared__ uint16_t mlnA[4][16 * 72]; // 9216 B: per-wave A staging [row=si*4+rl][d]
  __shared__ uint16_t kvS[4][1024];     // 8192 B: per-wave kv staging [r4][s16][c16]

  const int tid = threadIdx.x;
  const int w = tid >> 6, lane = tid & 63;
  const int rl = lane >> 4, c4 = lane & 15;
  const int sc = blockIdx.x;
  const int s0 = sc * 64;
  const int r0w = blockIdx.y * 16 + w * 4;

#pragma unroll
  for (int i = 0; i < 4; ++i) {
    const int e = i * 256 + tid;         // 1024 elems
    const int n = e >> 6, d = e & 63;
    const float val = (n < 8) ? Wk[d * 8 + n] : Wv[d * 8 + (n - 8)];
    WkvT[n * 72 + d] = f2bf_hw(val);
  }
  const float4 lngv = ((const float4*)lng)[c4];
  const float4 lnbv = ((const float4*)lnb)[c4];
  __syncthreads();

  // B fragments: B[n = c4][k = rl*8 + j (+32)]
  const short8 b0 = *(const short8*)&WkvT[c4 * 72 + rl * 8];
  const short8 b1 = *(const short8*)&WkvT[c4 * 72 + 32 + rl * 8];

  uint16_t* mA = mlnA[w];
  uint16_t* kS = kvS[w];

  float qacc[4] = {0.f, 0.f, 0.f, 0.f};
  float cacc = 0.f;

  // prime group 0 (1KB contiguous per wave instruction)
  float4 xg[4];
  float mv[4];
#pragma unroll
  for (int si = 0; si < 4; ++si) {
    const size_t grow = (size_t)(s0 + si) * R_DIM + r0w + rl;
    xg[si] = ((const float4*)(M + grow * 64))[c4];
    mv[si] = mask[grow];
  }

#pragma unroll 2
  for (int grp = 0; grp < 16; ++grp) {
    // prefetch next group while this one is processed (latency cover)
    const int gn = (grp < 15) ? grp + 1 : 15;
    float4 xn[4];
    float mn[4];
#pragma unroll
    for (int si = 0; si < 4; ++si) {
      const size_t grow = (size_t)(s0 + gn * 4 + si) * R_DIM + r0w + rl;
      xn[si] = ((const float4*)(M + grow * 64))[c4];
      mn[si] = mask[grow];
    }

#pragma unroll
    for (int si = 0; si < 4; ++si) {
      const float4 x = xg[si];
      float sum = x.x + x.y + x.z + x.w;
      float ss = x.x * x.x + x.y * x.y + x.z * x.z + x.w * x.w;
#pragma unroll
      for (int off = 1; off < 16; off <<= 1) {
        sum += __shfl_xor(sum, off, 64);
        ss  += __shfl_xor(ss, off, 64);
      }
      const float mu = sum * (1.f / 64.f);
      const float var = ss * (1.f / 64.f) - mu * mu;
      const float rstd = 1.f / sqrtf(var + 1e-5f);
      float y[4];
      y[0] = (x.x - mu) * rstd * lngv.x + lnbv.x;
      y[1] = (x.y - mu) * rstd * lngv.y + lnbv.y;
      y[2] = (x.z - mu) * rstd * lngv.z + lnbv.z;
      y[3] = (x.w - mu) * rstd * lngv.w + lnbv.w;
      uint2 p;
      p.x = pk2bf(y[0], y[1]);
      p.y = pk2bf(y[2], y[3]);
      *(uint2*)&mA[(si * 4 + rl) * 72 + c4 * 4] = p;
      const float m = mv[si];
      qacc[0] += m * y[0]; qacc[1] += m * y[1];
      qacc[2] += m * y[2]; qacc[3] += m * y[3];
      cacc += m;
    }
    // MFMA: A[row = si*4 + r_off][k=d]; lane reads row=c4, kslice=rl*8.
    const short8 a0 = *(const short8*)&mA[c4 * 72 + rl * 8];
    const short8 a1 = *(const short8*)&mA[c4 * 72 + 32 + rl * 8];
    floatx4 c = {0.f, 0.f, 0.f, 0.f};
    c = __builtin_amdgcn_mfma_f32_16x16x32_bf16(a0, b0, c, 0, 0, 0);
    c = __builtin_amdgcn_mfma_f32_16x16x32_bf16(a1, b1, c, 0, 0, 0);
    // C/D: row = rl*4 + i -> si = rl, r_off = i; col n = c4.
#pragma unroll
    for (int i = 0; i < 4; ++i)
      kS[i * 256 + ((grp & 3) * 4 + rl) * 16 + c4] = f2bf_hw(c[i]);

    // dump a completed 16-s block: per (r,t) 16 lanes x 8B = 128B dense
    if ((grp & 3) == 3) {
      const int sb = grp >> 2;
      const int rI = lane >> 4, li = lane & 15;
#pragma unroll
      for (int t = 0; t < 4; ++t) {
        const uint2 val = *(const uint2*)&kS[rI * 256 + t * 64 + li * 4];
        *(uint2*)(kv + ((size_t)(r0w + rI) * S_DIM + s0 + sb * 16) * 16 + t * 64 + li * 4) = val;
      }
    }
#pragma unroll
    for (int si = 0; si < 4; ++si) { xg[si] = xn[si]; mv[si] = mn[si]; }
  }

  // q partials: lane owns (r = r0w+rl, d = c4*4..+3) summed over this chunk
  *(float4*)&qpart[((size_t)(r0w + rl) * NCH + sc) * 72 + c4 * 4] =
      make_float4(qacc[0], qacc[1], qacc[2], qacc[3]);
  if (c4 == 0)
    qpart[((size_t)(r0w + rl) * NCH + sc) * 72 + 64] = cacc;
}

// ---------------- K2: q, logits, softmax, o ----------------
__global__ __launch_bounds__(256) void k2_attn(
    const float* __restrict__ Wq, const float* __restrict__ mask,
    const uint16_t* __restrict__ kv, const float* __restrict__ qpart,
    float* __restrict__ oG)
{
  __shared__ float qavgL[64];
  __shared__ __align__(16) float qLs[64];
  __shared__ float redmax[4][8], redden[4][8], redo[4][64];
  __shared__ float cntL;
  const int tid = threadIdx.x;
  const int r = blockIdx.x;
  const int lane = tid & 63, wv = tid >> 6;

  float qs = 0.f;
  if (tid < 65) {
#pragma unroll
    for (int c = 0; c < NCH; ++c) qs += qpart[((size_t)r * NCH + c) * 72 + tid];
    if (tid == 64) cntL = qs;
  }
  __syncthreads();
  if (tid < 64) qavgL[tid] = qs / (cntL + 1e-10f);
  __syncthreads();
  if (tid < 64) {
    float a = 0.f;
    for (int d = 0; d < 64; ++d) a += qavgL[d] * Wq[d * 64 + tid];
    qLs[tid] = a * 0.35355339059327373f;  // C^-0.5
  }
  __syncthreads();

  float l[64];
  float lm[8];
#pragma unroll
  for (int h = 0; h < 8; ++h) lm[h] = -3.0e38f;
  const uint4* kvp = (const uint4*)kv;
  const float4* q4 = (const float4*)qLs;
#pragma unroll
  for (int it = 0; it < 8; ++it) {
    const int s = it * 256 + tid;
    uint4 kw = kvp[((size_t)r * S_DIM + s) * 2];
    float k[8]; unpack8(kw, k);
    const float bias = (mask[(size_t)s * R_DIM + r] - 1.f) * 1e9f;
#pragma unroll
    for (int h = 0; h < 8; ++h) {
      const float4 qa = q4[h * 2], qb = q4[h * 2 + 1];
      float t = bias;
      t += qa.x * k[0] + qa.y * k[1] + qa.z * k[2] + qa.w * k[3];
      t += qb.x * k[4] + qb.y * k[5] + qb.z * k[6] + qb.w * k[7];
      l[it * 8 + h] = t;
      lm[h] = fmaxf(lm[h], t);
    }
  }
#pragma unroll
  for (int h = 0; h < 8; ++h)
#pragma unroll
    for (int off = 1; off < 64; off <<= 1) lm[h] = fmaxf(lm[h], __shfl_xor(lm[h], off, 64));
  if (lane == 0) {
#pragma unroll
    for (int h = 0; h < 8; ++h) redmax[wv][h] = lm[h];
  }
  __syncthreads();
  float gm[8];
#pragma unroll
  for (int h = 0; h < 8; ++h)
    gm[h] = fmaxf(fmaxf(redmax[0][h], redmax[1][h]), fmaxf(redmax[2][h], redmax[3][h]));

  float den[8], ao[64];
#pragma unroll
  for (int h = 0; h < 8; ++h) den[h] = 0.f;
#pragma unroll
  for (int i = 0; i < 64; ++i) ao[i] = 0.f;
#pragma unroll
  for (int it = 0; it < 8; ++it) {
    const int s = it * 256 + tid;
    uint4 vw = kvp[((size_t)r * S_DIM + s) * 2 + 1];
    float v[8]; unpack8(vw, v);
#pragma unroll
    for (int h = 0; h < 8; ++h) {
      const float w = __expf(l[it * 8 + h] - gm[h]);
      den[h] += w;
#pragma unroll
      for (int c = 0; c < 8; ++c) ao[h * 8 + c] += w * v[c];
    }
  }
  // fold-exchange ao: lane L ends with the wave sum for hc=L in ao[0]
#pragma unroll
  for (int st = 5; st >= 0; --st) {
    const int dist = 1 << st;
    const bool hi = (lane & dist) != 0;
#pragma unroll
    for (int j = 0; j < (1 << st); ++j) {
      const float send = hi ? ao[j] : ao[j + dist];
      const float recv = __shfl_xor(send, dist, 64);
      ao[j] = (hi ? ao[j + dist] : ao[j]) + recv;
    }
  }
#pragma unroll
  for (int h = 0; h < 8; ++h)
#pragma unroll
    for (int off = 1; off < 64; off <<= 1) den[h] += __shfl_xor(den[h], off, 64);

  redo[wv][lane] = ao[0];
  if (lane == 0) {
#pragma unroll
    for (int h = 0; h < 8; ++h) redden[wv][h] = den[h];
  }
  __syncthreads();
  if (tid < 64) {
    const float o = redo[0][tid] + redo[1][tid] + redo[2][tid] + redo[3][tid];
    const int h = tid >> 3;
    const float dd = redden[0][h] + redden[1][h] + redden[2][h] + redden[3][h];
    oG[(size_t)r * 64 + tid] = o / dd;
  }
}

// ---------------- K3: streaming LN -> gate MFMA -> out MFMA -> residual ----------------
// Same tiling as K1, now with the same next-group M prefetch: the 403MB
// M+out stream was the largest latency-exposed load in the pipeline.
__global__ __launch_bounds__(256, 3) void k3_out(
    const float* __restrict__ M, const float* __restrict__ oG,
    const float* __restrict__ Wg, const float* __restrict__ bg,
    const float* __restrict__ Wo, const float* __restrict__ bo,
    const float* __restrict__ lng, const float* __restrict__ lnb,
    float* __restrict__ out)
{
  __shared__ uint16_t WgT[64 * 72];     // WgT[hc][d] = Wg[d][hc]
  __shared__ uint16_t WoT[64 * 72];     // WoT[d][hc] = Wo[hc][d]
  __shared__ uint16_t mlnA[4][16 * 72]; // per-wave: mln A staging, reused for OUT
  __shared__ uint16_t tA[4][16 * 72];   // per-wave: gated T staging

  const int tid = threadIdx.x;
  const int w = tid >> 6, lane = tid & 63;
  const int rl = lane >> 4, c4 = lane & 15;
  const int sc = blockIdx.x;
  const int s0 = sc * 64;
  const int r0w = blockIdx.y * 16 + w * 4;

#pragma unroll
  for (int i = 0; i < 16; ++i) {
    const int idx = i * 256 + tid;        // 4096 weight elems
    const int a = idx >> 6, b = idx & 63;
    WgT[b * 72 + a] = f2bf_hw(Wg[idx]);   // a=d, b=hc
    WoT[b * 72 + a] = f2bf_hw(Wo[idx]);   // a=hc, b=d
  }
  const float4 lngv = ((const float4*)lng)[c4];
  const float4 lnbv = ((const float4*)lnb)[c4];
  __syncthreads();

  // B fragments: B[n = nt*16+c4][k-slice = kk*32 + rl*8]
  short8 wgB[4][2], woB[4][2];
#pragma unroll
  for (int nt = 0; nt < 4; ++nt)
#pragma unroll
    for (int kk = 0; kk < 2; ++kk) {
      wgB[nt][kk] = *(const short8*)&WgT[(nt * 16 + c4) * 72 + kk * 32 + rl * 8];
      woB[nt][kk] = *(const short8*)&WoT[(nt * 16 + c4) * 72 + kk * 32 + rl * 8];
    }
  float og[4][4], bgr[4], bor[4];
#pragma unroll
  for (int nt = 0; nt < 4; ++nt) {
    bgr[nt] = bg[nt * 16 + c4];
    bor[nt] = bo[nt * 16 + c4];
#pragma unroll
    for (int i = 0; i < 4; ++i)
      og[nt][i] = oG[(size_t)(r0w + i) * 64 + nt * 16 + c4];
  }

  uint16_t* mA = mlnA[w];
  uint16_t* tAw = tA[w];

  // prime group 0
  float4 xg[4];
#pragma unroll
  for (int si = 0; si < 4; ++si)
    xg[si] = ((const float4*)(M + ((size_t)(s0 + si) * R_DIM + r0w + rl) * 64))[c4];

#pragma unroll 2
  for (int grp = 0; grp < 16; ++grp) {
    const int sg = s0 + grp * 4;
    // prefetch next group (latency cover under LN+GEMM1+GEMM2)
    const int gn = (grp < 15) ? grp + 1 : 15;
    float4 xn[4];
#pragma unroll
    for (int si = 0; si < 4; ++si)
      xn[si] = ((const float4*)(M + ((size_t)(s0 + gn * 4 + si) * R_DIM + r0w + rl) * 64))[c4];

#pragma unroll
    for (int si = 0; si < 4; ++si) {
      const float4 x = xg[si];
      float sum = x.x + x.y + x.z + x.w;
      float ss = x.x * x.x + x.y * x.y + x.z * x.z + x.w * x.w;
#pragma unroll
      for (int off = 1; off < 16; off <<= 1) {
        sum += __shfl_xor(sum, off, 64);
        ss  += __shfl_xor(ss, off, 64);
      }
      const float mu = sum * (1.f / 64.f);
      const float var = ss * (1.f / 64.f) - mu * mu;
      const float rstd = 1.f / sqrtf(var + 1e-5f);
      float y[4];
      y[0] = (x.x - mu) * rstd * lngv.x + lnbv.x;
      y[1] = (x.y - mu) * rstd * lngv.y + lnbv.y;
      y[2] = (x.z - mu) * rstd * lngv.z + lnbv.z;
      y[3] = (x.w - mu) * rstd * lngv.w + lnbv.w;
      uint2 p;
      p.x = pk2bf(y[0], y[1]);
      p.y = pk2bf(y[2], y[3]);
      *(uint2*)&mA[(si * 4 + rl) * 72 + c4 * 4] = p;
    }

    // GEMM1: G = mln @ Wg; T = sigmoid(G+bg)*o  (C/D: row = rl*4+i -> si=rl, r_off=i)
    {
      const short8 a0 = *(const short8*)&mA[c4 * 72 + rl * 8];
      const short8 a1 = *(const short8*)&mA[c4 * 72 + 32 + rl * 8];
#pragma unroll
      for (int nt = 0; nt < 4; ++nt) {
        floatx4 c = {0.f, 0.f, 0.f, 0.f};
        c = __builtin_amdgcn_mfma_f32_16x16x32_bf16(a0, wgB[nt][0], c, 0, 0, 0);
        c = __builtin_amdgcn_mfma_f32_16x16x32_bf16(a1, wgB[nt][1], c, 0, 0, 0);
#pragma unroll
        for (int i = 0; i < 4; ++i) {
          const float z = c[i] + bgr[nt];
          const float gt = 1.0f / (1.0f + __expf(-z));
          tAw[(rl * 4 + i) * 72 + nt * 16 + c4] = f2bf_hw(gt * og[nt][i]);
        }
      }
    }
    // GEMM2: OUT = T @ Wo + bo -> mA (reuse)
    {
      const short8 a0 = *(const short8*)&tAw[c4 * 72 + rl * 8];
      const short8 a1 = *(const short8*)&tAw[c4 * 72 + 32 + rl * 8];
#pragma unroll
      for (int nt = 0; nt < 4; ++nt) {
        floatx4 c = {0.f, 0.f, 0.f, 0.f};
        c = __builtin_amdgcn_mfma_f32_16x16x32_bf16(a0, woB[nt][0], c, 0, 0, 0);
        c = __builtin_amdgcn_mfma_f32_16x16x32_bf16(a1, woB[nt][1], c, 0, 0, 0);
#pragma unroll
        for (int i = 0; i < 4; ++i)
          mA[(rl * 4 + i) * 72 + nt * 16 + c4] = f2bf_hw(c[i] + bor[nt]);
      }
    }
    // residual + coalesced store (x from registers; 1KB contiguous per instr)
#pragma unroll
    for (int si = 0; si < 4; ++si) {
      const uint2 tv = *(const uint2*)&mA[(si * 4 + rl) * 72 + c4 * 4];
      const float4 x = xg[si];
      float4 o;
      o.x = x.x + bf2f(tv.x & 0xffff);
      o.y = x.y + bf2f(tv.x >> 16);
      o.z = x.z + bf2f(tv.y & 0xffff);
      o.w = x.w + bf2f(tv.y >> 16);
      ((float4*)(out + ((size_t)(sg + si) * R_DIM + r0w + rl) * 64))[c4] = o;
    }
#pragma unroll
    for (int si = 0; si < 4; ++si) xg[si] = xn[si];
  }
}

extern "C" void kernel_launch(void* const* d_in, const int* in_sizes, int n_in,
                              void* d_out, int out_size, void* d_ws, size_t ws_size,
                              hipStream_t stream)
{
  const float* M    = (const float*)d_in[0];
  const float* mask = (const float*)d_in[1];
  const float* lng  = (const float*)d_in[2];
  const float* lnb  = (const float*)d_in[3];
  const float* Wq   = (const float*)d_in[4];
  const float* Wk   = (const float*)d_in[5];
  const float* Wv   = (const float*)d_in[6];
  const float* Wg   = (const float*)d_in[7];
  const float* bg   = (const float*)d_in[8];
  const float* Wo   = (const float*)d_in[9];
  const float* bo   = (const float*)d_in[10];
  float* out = (float*)d_out;

  char* ws = (char*)d_ws;
  uint16_t* kvB  = (uint16_t*)(ws + KV_OFF);
  float* qpartB  = (float*)(ws + QPART_OFF);
  float* oB      = (float*)(ws + O_OFF);

  k1_ln_kv<<<dim3(NCH, 24), 256, 0, stream>>>(M, mask, lng, lnb, Wk, Wv, kvB, qpartB);
  k2_attn<<<dim3(R_DIM), 256, 0, stream>>>(Wq, mask, kvB, qpartB, oB);
  k3_out<<<dim3(NCH, 24), 256, 0, stream>>>(M, oB, Wg, bg, Wo, bo, lng, lnb, out);
}